// Round 19
// baseline (633.947 us; speedup 1.0000x reference)
//
#include <hip/hip_runtime.h>
#include <hip/hip_bf16.h>
#include <math.h>

// Problem constants (match reference)
#define LAYERS 4
#define DMODEL 768
#define NHEAD 12
#define HDIM 64
#define FFDIM 3072
#define VOCAB 32000
#define NCLS 2
#define BATCH 8
#define SEQ 512
#define NTOK (BATCH * SEQ)   // 4096
#define QKVN (3 * DMODEL)    // 2304

typedef __attribute__((ext_vector_type(8))) short short8;      // 8 bf16 (4 VGPR)
typedef __attribute__((ext_vector_type(8))) unsigned short ushortx8;
typedef __attribute__((ext_vector_type(4))) unsigned short ushortx4;
typedef __attribute__((ext_vector_type(4))) float f32x4;

__device__ __forceinline__ float bf2f(unsigned short u) {
  return __uint_as_float(((unsigned)u) << 16);
}
__device__ __forceinline__ unsigned short f2bf(float x) {
  unsigned u = __float_as_uint(x);
  unsigned r = (u + 0x7fffu + ((u >> 16) & 1u)) >> 16;   // RNE
  return (unsigned short)r;
}

// async global->LDS, 16 bytes per lane (lds ptr = wave-uniform base + lane*16)
__device__ __forceinline__ void gload16(const void* gp, void* lp) {
  __builtin_amdgcn_global_load_lds(
      (const __attribute__((address_space(1))) void*)((unsigned long long)gp),
      (__attribute__((address_space(3))) void*)((unsigned int)(unsigned long long)lp),
      16, 0, 0);
}

// ---------------------------------------------------------------------------
// Embedding + positional encoding; writes bf16 xb (the residual stream)
// ---------------------------------------------------------------------------
__global__ __launch_bounds__(256) void embed_kernel(
    const int* __restrict__ text, const float* __restrict__ emb,
    unsigned short* __restrict__ xb) {
  int n = blockIdx.x;
  int t = threadIdx.x;
  int tok = text[n];
  int s = n % SEQ;
  const float sqrtD = 27.712812921102035f;
  const float nlog10k_over_d = -9.210340371976184f / 768.0f;
  #pragma unroll
  for (int i = 0; i < 3; ++i) {
    int d = t + i * 256;
    int j = d >> 1;
    float freq = expf((float)(2 * j) * nlog10k_over_d);
    float ang = (float)s * freq;
    float pe = (d & 1) ? cosf(ang) : sinf(ang);
    float val = emb[(size_t)tok * DMODEL + d] * sqrtD + pe;
    xb[(size_t)n * DMODEL + d] = f2bf(val);
  }
}

// ---------------------------------------------------------------------------
// Weight convert+transpose into TILED layout (R15 form; ~56us floor across 4
// structural variants -- latency/DRAM-page-bound, accepted, do not touch).
//   Wt[(n>>6)*(K>>6) + (k>>6)][n&63][k&63]  (each 64x64 tile = 8KB contiguous)
// ---------------------------------------------------------------------------
__global__ __launch_bounds__(256) void wconv_all_kernel(
    const float* __restrict__ Wq, const float* __restrict__ Wk,
    const float* __restrict__ Wv, const float* __restrict__ Wo,
    const float* __restrict__ W1, const float* __restrict__ W2,
    unsigned short* __restrict__ wqkvT, unsigned short* __restrict__ woT,
    unsigned short* __restrict__ w1T, unsigned short* __restrict__ w2T) {
  __shared__ float t[2][64][65];
  const size_t WDD = (size_t)DMODEL * DMODEL;
  const size_t WDF = (size_t)DMODEL * FFDIM;
  int l = blockIdx.x / 432;
  int blk = blockIdx.x % 432;
  const float* W; unsigned short* Wt; int K, N, tx, tys;
  if (blk < 144) {
    int region = blk / 36, r = blk % 36;
    tx = r % 12; tys = r / 12; K = DMODEL; N = DMODEL;
    W = (region == 0) ? (Wq + l * WDD) : (region == 1) ? (Wk + l * WDD)
      : (region == 2) ? (Wv + l * WDD) : (Wo + l * WDD);
    Wt = (region < 3) ? (wqkvT + (size_t)l * 3 * WDD + (size_t)region * WDD)
                      : (woT + (size_t)l * WDD);
  } else if (blk < 288) {
    int r = blk - 144; tx = r % 48; tys = r / 48; K = DMODEL; N = FFDIM;
    W = W1 + l * WDF; Wt = w1T + (size_t)l * WDF;
  } else {
    int r = blk - 288; tx = r % 12; tys = r / 12; K = FFDIM; N = DMODEL;
    W = W2 + l * WDF; Wt = w2T + (size_t)l * WDF;
  }
  const int n0 = tx * 64;
  const int tid = threadIdx.x;
  const int cc = (tid & 15) * 4, rbase = tid >> 4;  // read-phase coords
  const int wn = tid >> 3, k8 = (tid & 7) * 8;      // write-phase coords

  {
    const int k0 = tys * 256;
    #pragma unroll
    for (int j = 0; j < 4; ++j) {
      int r = j * 16 + rbase;
      float4 vv = *(const float4*)(W + (size_t)(k0 + r) * N + n0 + cc);
      t[0][r][cc + 0] = vv.x; t[0][r][cc + 1] = vv.y;
      t[0][r][cc + 2] = vv.z; t[0][r][cc + 3] = vv.w;
    }
  }
  #pragma unroll
  for (int i = 0; i < 4; ++i) {
    __syncthreads();
    const int k0 = tys * 256 + i * 64;
    unsigned short* tile = Wt + ((size_t)(n0 >> 6) * (K >> 6) + (k0 >> 6)) * 4096;
    #pragma unroll
    for (int half = 0; half < 2; ++half) {
      int nn = wn + half * 32;
      ushortx8 u;
      #pragma unroll
      for (int j = 0; j < 8; ++j) u[j] = f2bf(t[i & 1][k8 + j][nn]);
      *(ushortx8*)(tile + nn * 64 + k8) = u;
    }
    if (i < 3) {
      const int k0n = k0 + 64;
      #pragma unroll
      for (int j = 0; j < 4; ++j) {
        int r = j * 16 + rbase;
        float4 vv = *(const float4*)(W + (size_t)(k0n + r) * N + n0 + cc);
        t[(i + 1) & 1][r][cc + 0] = vv.x; t[(i + 1) & 1][r][cc + 1] = vv.y;
        t[(i + 1) & 1][r][cc + 2] = vv.z; t[(i + 1) & 1][r][cc + 3] = vv.w;
      }
    }
  }
}

// ---------------------------------------------------------------------------
// bf16 MFMA GEMM: C[M][N] = A[M][Kfull] @ Wt^T + bias, Wt in TILED layout.
// BM=128 x TBN, BK=64, 4 waves, 1D chunked XCD swizzle.
// TBN=128: SINGLE-buffered, 3 blocks/CU (R17-measured). TBN=64: dbuf, 3/CU.
// Split-K via gridDim.z: z=0 -> Cout (+bias), z=1 -> Cout2; partials combined
// by the 3-input LN (R12 lesson: adds belong in the coalesced LN stream).
// QKV mode (vTout != null): Q region (c < DMODEL) PRE-SCALED by 0.125
// (power-of-2 -> bit-exact in bf16) so attention skips the S scale.
//
// LDS swizzle invariant (both sides): staging stores global k-group g of row
// r at slot g ^ (r&7); fragment rows have r&7 == lane&7, and lane needs
// global group (lane>>4) + kh*4, so the read slot is
//   gs = (lane>>4) ^ (lane&7) ^ (kh*4)      [VERIFIED round 4/6; do NOT
// algebraically "simplify" -- round 5 broke correctness that way.]
// ---------------------------------------------------------------------------
#define BM 128
#define BK 64
template <int TBN>
__global__ __launch_bounds__(256, 3) void gemm_mfma_kernel(
    const unsigned short* __restrict__ A,    // [M][Kfull] bf16
    const unsigned short* __restrict__ Bt,   // tiled weights
    const float* __restrict__ bias,          // [N] (or Q region)
    const float* __restrict__ biasK,         // K region (QKV mode)
    const float* __restrict__ biasV,         // V region (QKV mode)
    void* __restrict__ Cout,                 // [M][N] f32 or bf16 (z==0)
    void* __restrict__ Cout2,                // [M][N] output for z==1
    unsigned short* __restrict__ vTout,      // QKV mode V^T output
    int M, int N, int Kfull, int Klen, int out_bf16, int relu) {
  constexpr int NF = TBN / 32;               // n-fragments per wave
  constexpr int NBUF = (TBN == 128) ? 1 : 2;
  __shared__ unsigned short As[NBUF][BM * BK];
  __shared__ unsigned short Bs[NBUF][TBN * BK];

  const int tid = threadIdx.x;
  const int lane = tid & 63;
  const int wave = tid >> 6;
  const int koff = blockIdx.z * Klen;

  // XCD swizzle: hardware block orig -> logical tile swz (x-first chunks)
  unsigned nwg = gridDim.x * gridDim.y;
  unsigned orig = blockIdx.y * gridDim.x + blockIdx.x;
  unsigned swz = (orig & 7) * (nwg >> 3) + (orig >> 3);
  const int m0 = (swz / gridDim.x) * BM;
  const int n0 = (swz % gridDim.x) * TBN;

  const int wrow = (wave >> 1) * 64;
  const int wcol = (wave & 1) * (TBN / 2);

  const int lrow = lane >> 3;
  const int kgrp = (lane & 7) ^ lrow;

  const unsigned short* Ab = A + (size_t)(m0 + 32 * wave + lrow) * Kfull + koff + kgrp * 8;
  const int rnW = (TBN / 4) * wave + lrow;   // B row base (wave-relative)
  const int ktiles = Kfull >> 6;
  const int AsWoff = wave * 2048 + lane * 8;
  const int BsWoff = wave * (TBN / 4) * BK + lane * 8;

  f32x4 acc[4][NF];
  #pragma unroll
  for (int m = 0; m < 4; ++m)
    #pragma unroll
    for (int n = 0; n < NF; ++n)
      acc[m][n] = (f32x4){0.f, 0.f, 0.f, 0.f};

  const int g0 = (lane >> 4) ^ (lane & 7);

  if constexpr (NBUF == 1) {
    // ---- single-buffered 2-barrier loop (high-occupancy TLP covers) ----
    for (int k0 = 0; k0 < Klen; k0 += BK) {
      __syncthreads();
      const int kt2 = (koff + k0) >> 6;
      #pragma unroll
      for (int i = 0; i < 4; ++i)
        gload16(Ab + (size_t)(8 * i) * Kfull + k0, As[0] + AsWoff + i * 512);
      #pragma unroll
      for (int i = 0; i < NF; ++i) {
        int nn = n0 + rnW + 8 * i;
        gload16(Bt + ((size_t)(nn >> 6) * ktiles + kt2) * 4096 + (nn & 63) * 64 + kgrp * 8,
                Bs[0] + BsWoff + i * 512);
      }
      __syncthreads();
      #pragma unroll
      for (int kh = 0; kh < 2; ++kh) {
        const int gs = g0 ^ (kh * 4);
        short8 a[4], b[NF];
        #pragma unroll
        for (int m = 0; m < 4; ++m) {
          int r = wrow + m * 16 + (lane & 15);
          a[m] = *(const short8*)(As[0] + r * 64 + gs * 8);
        }
        #pragma unroll
        for (int n = 0; n < NF; ++n) {
          int r = wcol + n * 16 + (lane & 15);
          b[n] = *(const short8*)(Bs[0] + r * 64 + gs * 8);
        }
        #pragma unroll
        for (int m = 0; m < 4; ++m)
          #pragma unroll
          for (int n = 0; n < NF; ++n)
            acc[m][n] = __builtin_amdgcn_mfma_f32_16x16x32_bf16(a[m], b[n], acc[m][n], 0, 0, 0);
      }
    }
  } else {
    // ---- double-buffered 1-barrier loop (R8-measured best for TBN=64) ----
    #pragma unroll
    for (int i = 0; i < 4; ++i)
      gload16(Ab + (size_t)(8 * i) * Kfull, As[0] + AsWoff + i * 512);
    #pragma unroll
    for (int i = 0; i < NF; ++i) {
      int nn = n0 + rnW + 8 * i;
      gload16(Bt + ((size_t)(nn >> 6) * ktiles + (koff >> 6)) * 4096 + (nn & 63) * 64 + kgrp * 8,
              Bs[0] + BsWoff + i * 512);
    }
    __syncthreads();

    int cur = 0;
    for (int k0 = 0; k0 < Klen; k0 += BK) {
      if (k0 + BK < Klen) {
        const int nxt = cur ^ 1;
        const int kt2 = (koff + k0 + BK) >> 6;
        #pragma unroll
        for (int i = 0; i < 4; ++i)
          gload16(Ab + (size_t)(8 * i) * Kfull + k0 + BK, As[nxt] + AsWoff + i * 512);
        #pragma unroll
        for (int i = 0; i < NF; ++i) {
          int nn = n0 + rnW + 8 * i;
          gload16(Bt + ((size_t)(nn >> 6) * ktiles + kt2) * 4096 + (nn & 63) * 64 + kgrp * 8,
                  Bs[nxt] + BsWoff + i * 512);
        }
      }
      #pragma unroll
      for (int kh = 0; kh < 2; ++kh) {
        const int gs = g0 ^ (kh * 4);
        short8 a[4], b[NF];
        #pragma unroll
        for (int m = 0; m < 4; ++m) {
          int r = wrow + m * 16 + (lane & 15);
          a[m] = *(const short8*)(As[cur] + r * 64 + gs * 8);
        }
        #pragma unroll
        for (int n = 0; n < NF; ++n) {
          int r = wcol + n * 16 + (lane & 15);
          b[n] = *(const short8*)(Bs[cur] + r * 64 + gs * 8);
        }
        #pragma unroll
        for (int m = 0; m < 4; ++m)
          #pragma unroll
          for (int n = 0; n < NF; ++n)
            acc[m][n] = __builtin_amdgcn_mfma_f32_16x16x32_bf16(a[m], b[n], acc[m][n], 0, 0, 0);
      }
      __syncthreads();
      cur ^= 1;
    }
  }

  void* outp = (blockIdx.z == 0) ? Cout : Cout2;
  const int crow0 = m0 + wrow + (lane >> 4) * 4;
  const int ccol0 = n0 + wcol + (lane & 15);
  #pragma unroll
  for (int n = 0; n < NF; ++n) {
    int c = ccol0 + n * 16;
    float bv = 0.f;
    if (blockIdx.z == 0) {
      if (vTout) bv = (c < DMODEL) ? bias[c]
                    : (c < 2 * DMODEL) ? biasK[c - DMODEL] : biasV[c - 2 * DMODEL];
      else bv = bias[c];
    }
    bool tovT = (vTout != nullptr) && (c >= 2 * DMODEL);
    bool qscale = (vTout != nullptr) && (c < DMODEL);
    int hd = c - 2 * DMODEL;   // h*64+d when tovT
    #pragma unroll
    for (int m = 0; m < 4; ++m) {
      #pragma unroll
      for (int r = 0; r < 4; ++r) {
        float val = acc[m][n][r] + bv;
        if (relu) val = fmaxf(val, 0.f);
        if (qscale) val *= 0.125f;
        int mr = crow0 + m * 16 + r;
        if (tovT) {
          vTout[((size_t)((mr >> 9) * NHEAD + (hd >> 6)) * HDIM + (hd & 63)) * SEQ + (mr & 511)] = f2bf(val);
        } else if (out_bf16) {
          ((unsigned short*)outp)[(size_t)mr * N + c] = f2bf(val);
        } else {
          ((float*)outp)[(size_t)mr * N + c] = val;
        }
      }
    }
  }
}

// ---------------------------------------------------------------------------
// MFMA flash attention, KVBLK=128. K double-buffered in LDS (1 barrier/iter);
// V read DIRECTLY from L2-resident vT (no staging; tile reused by 8 q-blocks
// -- guide common-mistake #7). Q pre-scaled 0.125 in QKV epilogue. setprio
// on MFMA clusters. K tile staging = 128 rows x 8 groups = 1024 chunks = 4
// iterations of 256 threads [R18 NaN bug: had 2 -> half-staged tile].
// LDS: 2x16KB Ks + 17KB Ps + 2KB mask = 51KB -> 3 blocks/CU.
// ---------------------------------------------------------------------------
#define KT 128
__global__ __launch_bounds__(256) void attention_mfma_kernel(
    const unsigned short* __restrict__ qkv,  // [NTOK][2304] bf16 (Q|K|V)
    const unsigned short* __restrict__ vT,   // [(b*H+h)*64+d][SEQ] bf16
    const int* __restrict__ mask,            // [B][SEQ]
    unsigned short* __restrict__ out) {      // [NTOK][768] bf16
  unsigned orig = blockIdx.x;
  unsigned blk = (orig & 7) * (gridDim.x >> 3) + (orig >> 3);
  int qt0 = (blk % (SEQ / 64)) * 64;
  int h = (blk / (SEQ / 64)) % NHEAD;
  int b = blk / ((SEQ / 64) * NHEAD);
  int tid = threadIdx.x, lane = tid & 63, wave = tid >> 6;

  __shared__ unsigned short Ks[2][KT * 64];   // dbuf [key][dimgrp ^ (key&7)]
  __shared__ unsigned short Ps[4][16 * 136];  // per-wave P[q][key], stride 136
  __shared__ int msk_s[SEQ];

  if (tid < SEQ / 4) *(int4*)&msk_s[tid * 4] = *(const int4*)&mask[b * SEQ + tid * 4];

  int qrow = qt0 + wave * 16 + (lane & 15);
  const unsigned short* qp = qkv + (size_t)(b * SEQ + qrow) * QKVN + h * HDIM + (lane >> 4) * 8;
  short8 qf0 = *(const short8*)qp;
  short8 qf1 = *(const short8*)(qp + 32);

  const unsigned short* vbase = vT + (size_t)(b * NHEAD + h) * HDIM * SEQ;

  float m_r[4], l_r[4];
  f32x4 acc_o[4];
  #pragma unroll
  for (int r = 0; r < 4; ++r) { m_r[r] = -3.0e38f; l_r[r] = 0.f; }
  #pragma unroll
  for (int n = 0; n < 4; ++n) acc_o[n] = (f32x4){0.f, 0.f, 0.f, 0.f};

  // prologue: stage K tile 0 into buffer 0 (1024 chunks; 4 per thread)
  #pragma unroll
  for (int it = 0; it < 4; ++it) {
    int ck = it * 256 + tid;
    int krow = ck >> 3, kg = ck & 7;
    gload16(qkv + (size_t)(b * SEQ + krow) * QKVN + DMODEL + h * HDIM + ((kg ^ (krow & 7)) * 8),
            Ks[0] + ck * 8);
  }
  __syncthreads();

  int cur = 0;
  for (int kt = 0; kt < SEQ / KT; ++kt) {
    // issue next K tile's loads into the other buffer (1024 chunks)
    if (kt + 1 < SEQ / KT) {
      const int nxt = cur ^ 1;
      #pragma unroll
      for (int it = 0; it < 4; ++it) {
        int ck = it * 256 + tid;
        int krow = ck >> 3, kg = ck & 7;
        gload16(qkv + (size_t)(b * SEQ + (kt + 1) * KT + krow) * QKVN + DMODEL + h * HDIM + ((kg ^ (krow & 7)) * 8),
                Ks[nxt] + ck * 8);
      }
    }

    // ---- S = Q K^T  (Q pre-scaled by 0.125) ----
    f32x4 acc_s[8];
    #pragma unroll
    for (int nf = 0; nf < 8; ++nf) acc_s[nf] = (f32x4){0.f, 0.f, 0.f, 0.f};
    __builtin_amdgcn_s_setprio(1);
    #pragma unroll
    for (int nf = 0; nf < 8; ++nf) {
      int rb = nf * 16 + (lane & 15);
      int G = lane >> 4;
      short8 kf0 = *(const short8*)(Ks[cur] + rb * 64 + ((G ^ (rb & 7)) * 8));
      short8 kf1 = *(const short8*)(Ks[cur] + rb * 64 + (((G + 4) ^ (rb & 7)) * 8));
      acc_s[nf] = __builtin_amdgcn_mfma_f32_16x16x32_bf16(qf0, kf0, acc_s[nf], 0, 0, 0);
      acc_s[nf] = __builtin_amdgcn_mfma_f32_16x16x32_bf16(qf1, kf1, acc_s[nf], 0, 0, 0);
    }
    __builtin_amdgcn_s_setprio(0);

    // ---- online softmax (mask in place, then exp) ----
    float rmax[4];
    #pragma unroll
    for (int r = 0; r < 4; ++r) rmax[r] = -3.0e38f;
    #pragma unroll
    for (int nf = 0; nf < 8; ++nf) {
      int msk = msk_s[kt * KT + nf * 16 + (lane & 15)];
      #pragma unroll
      for (int r = 0; r < 4; ++r) {
        float s = acc_s[nf][r];
        if (msk == 0) s = -1e9f;
        acc_s[nf][r] = s;
        rmax[r] = fmaxf(rmax[r], s);
      }
    }
    #pragma unroll
    for (int r = 0; r < 4; ++r) {
      rmax[r] = fmaxf(rmax[r], __shfl_xor(rmax[r], 1));
      rmax[r] = fmaxf(rmax[r], __shfl_xor(rmax[r], 2));
      rmax[r] = fmaxf(rmax[r], __shfl_xor(rmax[r], 4));
      rmax[r] = fmaxf(rmax[r], __shfl_xor(rmax[r], 8));
    }
    float corr[4], psum[4];
    #pragma unroll
    for (int r = 0; r < 4; ++r) {
      float mn = fmaxf(m_r[r], rmax[r]);
      corr[r] = expf(m_r[r] - mn);
      m_r[r] = mn;
      psum[r] = 0.f;
    }
    #pragma unroll
    for (int nf = 0; nf < 8; ++nf) {
      #pragma unroll
      for (int r = 0; r < 4; ++r) {
        float e = expf(acc_s[nf][r] - m_r[r]);
        psum[r] += e;
        Ps[wave][((lane >> 4) * 4 + r) * 136 + nf * 16 + (lane & 15)] = f2bf(e);
      }
    }
    #pragma unroll
    for (int r = 0; r < 4; ++r) {
      psum[r] += __shfl_xor(psum[r], 1);
      psum[r] += __shfl_xor(psum[r], 2);
      psum[r] += __shfl_xor(psum[r], 4);
      psum[r] += __shfl_xor(psum[r], 8);
      l_r[r] = l_r[r] * corr[r] + psum[r];
    }
    #pragma unroll
    for (int n = 0; n < 4; ++n)
      #pragma unroll
      for (int r = 0; r < 4; ++r)
        acc_o[n][r] *= corr[r];

    // ---- O += P V  (V fragments loaded directly from L2-resident vT) ----
    short8 pa[4];
    #pragma unroll
    for (int kh = 0; kh < 4; ++kh)
      pa[kh] = *(const short8*)(&Ps[wave][(lane & 15) * 136 + kh * 32 + (lane >> 4) * 8]);
    __builtin_amdgcn_s_setprio(1);
    #pragma unroll
    for (int nd = 0; nd < 4; ++nd) {
      int rb = nd * 16 + (lane & 15);
      const unsigned short* vrow = vbase + (size_t)rb * SEQ + kt * KT + (lane >> 4) * 8;
      #pragma unroll
      for (int kh = 0; kh < 4; ++kh) {
        short8 vf = *(const short8*)(vrow + kh * 32);
        acc_o[nd] = __builtin_amdgcn_mfma_f32_16x16x32_bf16(pa[kh], vf, acc_o[nd], 0, 0, 0);
      }
    }
    __builtin_amdgcn_s_setprio(0);

    __syncthreads();   // drains next K tile's loads; syncs buffer handoff
    cur ^= 1;
  }

  #pragma unroll
  for (int r = 0; r < 4; ++r) {
    float inv = 1.0f / l_r[r];
    int row = qt0 + wave * 16 + (lane >> 4) * 4 + r;
    unsigned short* op = out + (size_t)(b * SEQ + row) * DMODEL + h * HDIM + (lane & 15);
    #pragma unroll
    for (int n = 0; n < 4; ++n)
      op[n * 16] = f2bf(acc_o[n][r] * inv);
  }
}

// ---------------------------------------------------------------------------
// LayerNorm over the bf16 residual stream, wave-per-token (no LDS/barriers).
// out = LN(xin (+ o) (+ o2)) in bf16. Stats in f32. In-place-safe per row.
// ---------------------------------------------------------------------------
__global__ __launch_bounds__(256) void ln_kernel(
    const unsigned short* __restrict__ xin, const unsigned short* __restrict__ o,
    const unsigned short* __restrict__ o2,
    unsigned short* __restrict__ outb,
    const float* __restrict__ g, const float* __restrict__ bta) {
  int lane = threadIdx.x & 63, wave = threadIdx.x >> 6;
  int n = blockIdx.x * 4 + wave;
  size_t base = (size_t)n * DMODEL;

  float v[12];
  float sum = 0.f;
  #pragma unroll
  for (int c = 0; c < 3; ++c) {
    int off = c * 256 + lane * 4;
    ushortx4 xv = *(const ushortx4*)(xin + base + off);
    #pragma unroll
    for (int j = 0; j < 4; ++j) v[c * 4 + j] = bf2f(xv[j]);
    if (o) {
      ushortx4 ov = *(const ushortx4*)(o + base + off);
      #pragma unroll
      for (int j = 0; j < 4; ++j) v[c * 4 + j] += bf2f(ov[j]);
    }
    if (o2) {
      ushortx4 ov = *(const ushortx4*)(o2 + base + off);
      #pragma unroll
      for (int j = 0; j < 4; ++j) v[c * 4 + j] += bf2f(ov[j]);
    }
    #pragma unroll
    for (int j = 0; j < 4; ++j) sum += v[c * 4 + j];
  }
  #pragma unroll
  for (int s = 1; s < 64; s <<= 1) sum += __shfl_xor(sum, s);
  float mu = sum * (1.0f / DMODEL);
  float var = 0.f;
  #pragma unroll
  for (int i = 0; i < 12; ++i) {
    float d = v[i] - mu;
    var += d * d;
  }
  #pragma unroll
  for (int s = 1; s < 64; s <<= 1) var += __shfl_xor(var, s);
  float rstd = rsqrtf(var * (1.0f / DMODEL) + 1e-5f);

  #pragma unroll
  for (int c = 0; c < 3; ++c) {
    int off = c * 256 + lane * 4;
    float4 gv = *(const float4*)(g + off);
    float4 bv = *(const float4*)(bta + off);
    ushortx4 rb;
    rb[0] = f2bf((v[c * 4 + 0] - mu) * rstd * gv.x + bv.x);
    rb[1] = f2bf((v[c * 4 + 1] - mu) * rstd * gv.y + bv.y);
    rb[2] = f2bf((v[c * 4 + 2] - mu) * rstd * gv.z + bv.z);
    rb[3] = f2bf((v[c * 4 + 3] - mu) * rstd * gv.w + bv.w);
    *(ushortx4*)(outb + base + off) = rb;
  }
}

// ---------------------------------------------------------------------------
// Mean-pool, stage 1 (bf16 input): 8 seq chunks of 64 rows -> partial[c][b][d]
// ---------------------------------------------------------------------------
__global__ __launch_bounds__(256) void pool_part_kernel(
    const unsigned short* __restrict__ xin, float* __restrict__ partial) {
  int blk = blockIdx.x;
  int chunk = blk / (BATCH * 3);
  int rem = blk % (BATCH * 3);
  int b = rem / 3, dc = rem % 3;
  int d = dc * 256 + threadIdx.x;
  float s_ = 0.f;
  for (int s = chunk * 64; s < chunk * 64 + 64; ++s)
    s_ += bf2f(xin[(size_t)(b * SEQ + s) * DMODEL + d]);
  partial[((size_t)chunk * BATCH + b) * DMODEL + d] = s_;
}

// ---------------------------------------------------------------------------
// Classifier: reduce 8 pool partials, logits = pooled @ Wfc + bfc, log_softmax
// ---------------------------------------------------------------------------
__global__ __launch_bounds__(256) void classifier_kernel(
    const float* __restrict__ partial, const float* __restrict__ Wfc,
    const float* __restrict__ bfc, float* __restrict__ out) {
  int b = blockIdx.x;
  int t = threadIdx.x;
  __shared__ float s0[256], s1[256];
  float acc0 = 0.f, acc1 = 0.f;
  for (int d = t; d < DMODEL; d += 256) {
    float p = 0.f;
    #pragma unroll
    for (int c = 0; c < 8; ++c)
      p += partial[((size_t)c * BATCH + b) * DMODEL + d];
    p *= (1.0f / SEQ);
    acc0 += p * Wfc[d * NCLS + 0];
    acc1 += p * Wfc[d * NCLS + 1];
  }
  s0[t] = acc0; s1[t] = acc1; __syncthreads();
  for (int off = 128; off; off >>= 1) {
    if (t < off) { s0[t] += s0[t + off]; s1[t] += s1[t + off]; }
    __syncthreads();
  }
  if (t == 0) {
    float l0 = s0[0] + bfc[0], l1 = s1[0] + bfc[1];
    float m = fmaxf(l0, l1);
    float lse = m + logf(expf(l0 - m) + expf(l1 - m));
    out[b * NCLS + 0] = l0 - lse;
    out[b * NCLS + 1] = l1 - lse;
  }
}

// ---------------------------------------------------------------------------
extern "C" void kernel_launch(void* const* d_in, const int* in_sizes, int n_in,
                              void* d_out, int out_size, void* d_ws, size_t ws_size,
                              hipStream_t stream) {
  const int*   text  = (const int*)d_in[0];
  const int*   mask  = (const int*)d_in[1];
  const float* emb   = (const float*)d_in[2];
  const float* Wq    = (const float*)d_in[3];
  const float* bq    = (const float*)d_in[4];
  const float* Wk    = (const float*)d_in[5];
  const float* bk    = (const float*)d_in[6];
  const float* Wv    = (const float*)d_in[7];
  const float* bv    = (const float*)d_in[8];
  const float* Wo    = (const float*)d_in[9];
  const float* bo    = (const float*)d_in[10];
  const float* W1    = (const float*)d_in[11];
  const float* b1    = (const float*)d_in[12];
  const float* W2    = (const float*)d_in[13];
  const float* b2    = (const float*)d_in[14];
  const float* ln1_g = (const float*)d_in[15];
  const float* ln1_b = (const float*)d_in[16];
  const float* ln2_g = (const float*)d_in[17];
  const float* ln2_b = (const float*)d_in[18];
  const float* lnf_g = (const float*)d_in[19];
  const float* lnf_b = (const float*)d_in[20];
  const float* Wfc   = (const float*)d_in[21];
  const float* bfc   = (const float*)d_in[22];

  const size_t ND = (size_t)NTOK * DMODEL;
  const size_t NF = (size_t)NTOK * FFDIM;
  const size_t WDD = (size_t)DMODEL * DMODEL;
  const size_t WDF = (size_t)DMODEL * FFDIM;

  float* partial = (float*)d_ws;                  // [8][B][D] pool partials
  unsigned short* xb   = (unsigned short*)(partial + 8 * BATCH * DMODEL);  // [N,D] residual stream (bf16)
  unsigned short* qkvb = xb + ND;                 // [N,2304]; also o/ffn2 out
  unsigned short* vTb  = qkvb + (size_t)NTOK * QKVN;  // [B*H*64][SEQ]
  unsigned short* aob  = vTb + ND;                // [N,D] attn out / ffn2 partial1 / final-LN
  unsigned short* h1b  = aob + ND;                // [N,FF]; first ND = o-proj partial1
  unsigned short* wqkvT = h1b + NF;               // 4 x tiled [2304][768]
  unsigned short* woT  = wqkvT + 4 * 3 * WDD;     // 4 x tiled [768][768]
  unsigned short* w1T  = woT + 4 * WDD;           // 4 x tiled [FF][D]
  unsigned short* w2T  = w1T + 4 * WDF;           // 4 x tiled [D][FF]
  unsigned short* ob   = qkvb;                    // alias: o-proj/ffn2 output

  dim3 gD64s(DMODEL / 64, NTOK / BM, 2);   // split-K=2 -> 768 blocks, TBN=64
  dim3 gQKV(QKVN / 128, NTOK / BM);        // (18, 32) = 576 blocks, TBN=128
  dim3 gF(FFDIM / 128, NTOK / BM);         // (24, 32) = 768 blocks, TBN=128

  embed_kernel<<<NTOK, 256, 0, stream>>>(text, emb, xb);
  wconv_all_kernel<<<4 * 432, 256, 0, stream>>>(
      Wq, Wk, Wv, Wo, W1, W2, wqkvT, woT, w1T, w2T);

  for (int l = 0; l < LAYERS; ++l) {
    // fused QKV projection (V written transposed to vTb; Q pre-scaled 0.125)
    gemm_mfma_kernel<128><<<gQKV, 256, 0, stream>>>(
        xb, wqkvT + (size_t)l * 3 * WDD, bq + l * DMODEL, bk + l * DMODEL,
        bv + l * DMODEL, qkvb, nullptr, vTb, NTOK, QKVN, DMODEL, DMODEL, 1, 0);

    attention_mfma_kernel<<<BATCH * NHEAD * (SEQ / 64), 256, 0, stream>>>(
        qkvb, vTb, mask, aob);

    // O-proj split-K=2: z=0 -> ob (with bias), z=1 -> h1b (dead)
    gemm_mfma_kernel<64><<<gD64s, 256, 0, stream>>>(
        aob, woT + (size_t)l * WDD, bo + l * DMODEL, nullptr, nullptr,
        ob, h1b, nullptr, NTOK, DMODEL, DMODEL, DMODEL / 2, 1, 0);
    ln_kernel<<<NTOK / 4, 256, 0, stream>>>(xb, ob, h1b, xb,
                                            ln1_g + l * DMODEL, ln1_b + l * DMODEL);
    gemm_mfma_kernel<128><<<gF, 256, 0, stream>>>(
        xb, w1T + (size_t)l * WDF, b1 + l * FFDIM, nullptr, nullptr,
        h1b, nullptr, nullptr, NTOK, FFDIM, DMODEL, DMODEL, 1, 1);
    // FFN2 split-K=2: z=0 -> ob (with bias), z=1 -> aob (dead)
    gemm_mfma_kernel<64><<<gD64s, 256, 0, stream>>>(
        h1b, w2T + (size_t)l * WDF, b2 + l * DMODEL, nullptr, nullptr,
        ob, aob, nullptr, NTOK, DMODEL, FFDIM, FFDIM / 2, 1, 0);
    ln_kernel<<<NTOK / 4, 256, 0, stream>>>(xb, ob, aob, xb,
                                            ln2_g + l * DMODEL, ln2_b + l * DMODEL);
  }

  // final LN -> bf16 (into aob), then pool partials (bf16) + classify
  ln_kernel<<<NTOK / 4, 256, 0, stream>>>(xb, nullptr, nullptr, aob, lnf_g, lnf_b);
  pool_part_kernel<<<8 * BATCH * 3, 256, 0, stream>>>(aob, partial);
  classifier_kernel<<<BATCH, 256, 0, stream>>>(partial, Wfc, bfc, (float*)d_out);
}

// Round 20
// 596.863 us; speedup vs baseline: 1.0621x; 1.0621x over previous
//
#include <hip/hip_runtime.h>
#include <hip/hip_bf16.h>
#include <math.h>

// Problem constants (match reference)
#define LAYERS 4
#define DMODEL 768
#define NHEAD 12
#define HDIM 64
#define FFDIM 3072
#define VOCAB 32000
#define NCLS 2
#define BATCH 8
#define SEQ 512
#define NTOK (BATCH * SEQ)   // 4096
#define QKVN (3 * DMODEL)    // 2304

typedef __attribute__((ext_vector_type(8))) short short8;      // 8 bf16 (4 VGPR)
typedef __attribute__((ext_vector_type(8))) unsigned short ushortx8;
typedef __attribute__((ext_vector_type(4))) unsigned short ushortx4;
typedef __attribute__((ext_vector_type(4))) float f32x4;

__device__ __forceinline__ float bf2f(unsigned short u) {
  return __uint_as_float(((unsigned)u) << 16);
}
__device__ __forceinline__ unsigned short f2bf(float x) {
  unsigned u = __float_as_uint(x);
  unsigned r = (u + 0x7fffu + ((u >> 16) & 1u)) >> 16;   // RNE
  return (unsigned short)r;
}

// async global->LDS, 16 bytes per lane (lds ptr = wave-uniform base + lane*16)
__device__ __forceinline__ void gload16(const void* gp, void* lp) {
  __builtin_amdgcn_global_load_lds(
      (const __attribute__((address_space(1))) void*)((unsigned long long)gp),
      (__attribute__((address_space(3))) void*)((unsigned int)(unsigned long long)lp),
      16, 0, 0);
}

// ---------------------------------------------------------------------------
// Embedding + positional encoding; writes bf16 xb (the residual stream)
// ---------------------------------------------------------------------------
__global__ __launch_bounds__(256) void embed_kernel(
    const int* __restrict__ text, const float* __restrict__ emb,
    unsigned short* __restrict__ xb) {
  int n = blockIdx.x;
  int t = threadIdx.x;
  int tok = text[n];
  int s = n % SEQ;
  const float sqrtD = 27.712812921102035f;
  const float nlog10k_over_d = -9.210340371976184f / 768.0f;
  #pragma unroll
  for (int i = 0; i < 3; ++i) {
    int d = t + i * 256;
    int j = d >> 1;
    float freq = expf((float)(2 * j) * nlog10k_over_d);
    float ang = (float)s * freq;
    float pe = (d & 1) ? cosf(ang) : sinf(ang);
    float val = emb[(size_t)tok * DMODEL + d] * sqrtD + pe;
    xb[(size_t)n * DMODEL + d] = f2bf(val);
  }
}

// ---------------------------------------------------------------------------
// Weight convert+transpose into TILED layout (R15 form; ~56us floor across 4
// structural variants -- latency/DRAM-page-bound, accepted, do not touch).
//   Wt[(n>>6)*(K>>6) + (k>>6)][n&63][k&63]  (each 64x64 tile = 8KB contiguous)
// ---------------------------------------------------------------------------
__global__ __launch_bounds__(256) void wconv_all_kernel(
    const float* __restrict__ Wq, const float* __restrict__ Wk,
    const float* __restrict__ Wv, const float* __restrict__ Wo,
    const float* __restrict__ W1, const float* __restrict__ W2,
    unsigned short* __restrict__ wqkvT, unsigned short* __restrict__ woT,
    unsigned short* __restrict__ w1T, unsigned short* __restrict__ w2T) {
  __shared__ float t[2][64][65];
  const size_t WDD = (size_t)DMODEL * DMODEL;
  const size_t WDF = (size_t)DMODEL * FFDIM;
  int l = blockIdx.x / 432;
  int blk = blockIdx.x % 432;
  const float* W; unsigned short* Wt; int K, N, tx, tys;
  if (blk < 144) {
    int region = blk / 36, r = blk % 36;
    tx = r % 12; tys = r / 12; K = DMODEL; N = DMODEL;
    W = (region == 0) ? (Wq + l * WDD) : (region == 1) ? (Wk + l * WDD)
      : (region == 2) ? (Wv + l * WDD) : (Wo + l * WDD);
    Wt = (region < 3) ? (wqkvT + (size_t)l * 3 * WDD + (size_t)region * WDD)
                      : (woT + (size_t)l * WDD);
  } else if (blk < 288) {
    int r = blk - 144; tx = r % 48; tys = r / 48; K = DMODEL; N = FFDIM;
    W = W1 + l * WDF; Wt = w1T + (size_t)l * WDF;
  } else {
    int r = blk - 288; tx = r % 12; tys = r / 12; K = FFDIM; N = DMODEL;
    W = W2 + l * WDF; Wt = w2T + (size_t)l * WDF;
  }
  const int n0 = tx * 64;
  const int tid = threadIdx.x;
  const int cc = (tid & 15) * 4, rbase = tid >> 4;  // read-phase coords
  const int wn = tid >> 3, k8 = (tid & 7) * 8;      // write-phase coords

  {
    const int k0 = tys * 256;
    #pragma unroll
    for (int j = 0; j < 4; ++j) {
      int r = j * 16 + rbase;
      float4 vv = *(const float4*)(W + (size_t)(k0 + r) * N + n0 + cc);
      t[0][r][cc + 0] = vv.x; t[0][r][cc + 1] = vv.y;
      t[0][r][cc + 2] = vv.z; t[0][r][cc + 3] = vv.w;
    }
  }
  #pragma unroll
  for (int i = 0; i < 4; ++i) {
    __syncthreads();
    const int k0 = tys * 256 + i * 64;
    unsigned short* tile = Wt + ((size_t)(n0 >> 6) * (K >> 6) + (k0 >> 6)) * 4096;
    #pragma unroll
    for (int half = 0; half < 2; ++half) {
      int nn = wn + half * 32;
      ushortx8 u;
      #pragma unroll
      for (int j = 0; j < 8; ++j) u[j] = f2bf(t[i & 1][k8 + j][nn]);
      *(ushortx8*)(tile + nn * 64 + k8) = u;
    }
    if (i < 3) {
      const int k0n = k0 + 64;
      #pragma unroll
      for (int j = 0; j < 4; ++j) {
        int r = j * 16 + rbase;
        float4 vv = *(const float4*)(W + (size_t)(k0n + r) * N + n0 + cc);
        t[(i + 1) & 1][r][cc + 0] = vv.x; t[(i + 1) & 1][r][cc + 1] = vv.y;
        t[(i + 1) & 1][r][cc + 2] = vv.z; t[(i + 1) & 1][r][cc + 3] = vv.w;
      }
    }
  }
}

// ---------------------------------------------------------------------------
// bf16 MFMA GEMM: C[M][N] = A[M][Kfull] @ Wt^T + bias, Wt in TILED layout.
// BM=128 x TBN, BK=64, 4 waves, 1D chunked XCD swizzle.
// TBN=128: SINGLE-buffered, 3 blocks/CU (R17-measured: one occupancy round
//   beats dbuf's 2/CU tail-quantization). TBN=64: double-buffered, 3/CU.
// Split-K via gridDim.z: z=0 -> Cout (+bias), z=1 -> Cout2; partials combined
// by the 3-input LN (R12 lesson: adds belong in the coalesced LN stream).
// R19 lesson: V-direct global gathers in attention's PV loop regressed -34us;
// LDS staging of both K and V (this round's attention) is measured-best.
//
// LDS swizzle invariant (both sides): staging stores global k-group g of row
// r at slot g ^ (r&7); fragment rows have r&7 == lane&7, and lane needs
// global group (lane>>4) + kh*4, so the read slot is
//   gs = (lane>>4) ^ (lane&7) ^ (kh*4)      [VERIFIED round 4/6; do NOT
// algebraically "simplify" -- round 5 broke correctness that way.]
// ---------------------------------------------------------------------------
#define BM 128
#define BK 64
template <int TBN>
__global__ __launch_bounds__(256, 3) void gemm_mfma_kernel(
    const unsigned short* __restrict__ A,    // [M][Kfull] bf16
    const unsigned short* __restrict__ Bt,   // tiled weights
    const float* __restrict__ bias,          // [N] (or Q region)
    const float* __restrict__ biasK,         // K region (QKV mode)
    const float* __restrict__ biasV,         // V region (QKV mode)
    void* __restrict__ Cout,                 // [M][N] f32 or bf16 (z==0)
    void* __restrict__ Cout2,                // [M][N] output for z==1
    unsigned short* __restrict__ vTout,      // QKV mode V^T output
    int M, int N, int Kfull, int Klen, int out_bf16, int relu) {
  constexpr int NF = TBN / 32;               // n-fragments per wave
  constexpr int NBUF = (TBN == 128) ? 1 : 2;
  __shared__ unsigned short As[NBUF][BM * BK];
  __shared__ unsigned short Bs[NBUF][TBN * BK];

  const int tid = threadIdx.x;
  const int lane = tid & 63;
  const int wave = tid >> 6;
  const int koff = blockIdx.z * Klen;

  // XCD swizzle: hardware block orig -> logical tile swz (x-first chunks)
  unsigned nwg = gridDim.x * gridDim.y;
  unsigned orig = blockIdx.y * gridDim.x + blockIdx.x;
  unsigned swz = (orig & 7) * (nwg >> 3) + (orig >> 3);
  const int m0 = (swz / gridDim.x) * BM;
  const int n0 = (swz % gridDim.x) * TBN;

  const int wrow = (wave >> 1) * 64;
  const int wcol = (wave & 1) * (TBN / 2);

  const int lrow = lane >> 3;
  const int kgrp = (lane & 7) ^ lrow;

  const unsigned short* Ab = A + (size_t)(m0 + 32 * wave + lrow) * Kfull + koff + kgrp * 8;
  const int rnW = (TBN / 4) * wave + lrow;   // B row base (wave-relative)
  const int ktiles = Kfull >> 6;
  const int AsWoff = wave * 2048 + lane * 8;
  const int BsWoff = wave * (TBN / 4) * BK + lane * 8;

  f32x4 acc[4][NF];
  #pragma unroll
  for (int m = 0; m < 4; ++m)
    #pragma unroll
    for (int n = 0; n < NF; ++n)
      acc[m][n] = (f32x4){0.f, 0.f, 0.f, 0.f};

  const int g0 = (lane >> 4) ^ (lane & 7);

  if constexpr (NBUF == 1) {
    // ---- single-buffered 2-barrier loop (high-occupancy TLP covers) ----
    for (int k0 = 0; k0 < Klen; k0 += BK) {
      __syncthreads();
      const int kt2 = (koff + k0) >> 6;
      #pragma unroll
      for (int i = 0; i < 4; ++i)
        gload16(Ab + (size_t)(8 * i) * Kfull + k0, As[0] + AsWoff + i * 512);
      #pragma unroll
      for (int i = 0; i < NF; ++i) {
        int nn = n0 + rnW + 8 * i;
        gload16(Bt + ((size_t)(nn >> 6) * ktiles + kt2) * 4096 + (nn & 63) * 64 + kgrp * 8,
                Bs[0] + BsWoff + i * 512);
      }
      __syncthreads();
      #pragma unroll
      for (int kh = 0; kh < 2; ++kh) {
        const int gs = g0 ^ (kh * 4);
        short8 a[4], b[NF];
        #pragma unroll
        for (int m = 0; m < 4; ++m) {
          int r = wrow + m * 16 + (lane & 15);
          a[m] = *(const short8*)(As[0] + r * 64 + gs * 8);
        }
        #pragma unroll
        for (int n = 0; n < NF; ++n) {
          int r = wcol + n * 16 + (lane & 15);
          b[n] = *(const short8*)(Bs[0] + r * 64 + gs * 8);
        }
        #pragma unroll
        for (int m = 0; m < 4; ++m)
          #pragma unroll
          for (int n = 0; n < NF; ++n)
            acc[m][n] = __builtin_amdgcn_mfma_f32_16x16x32_bf16(a[m], b[n], acc[m][n], 0, 0, 0);
      }
    }
  } else {
    // ---- double-buffered 1-barrier loop (R8-measured best for TBN=64) ----
    #pragma unroll
    for (int i = 0; i < 4; ++i)
      gload16(Ab + (size_t)(8 * i) * Kfull, As[0] + AsWoff + i * 512);
    #pragma unroll
    for (int i = 0; i < NF; ++i) {
      int nn = n0 + rnW + 8 * i;
      gload16(Bt + ((size_t)(nn >> 6) * ktiles + (koff >> 6)) * 4096 + (nn & 63) * 64 + kgrp * 8,
              Bs[0] + BsWoff + i * 512);
    }
    __syncthreads();

    int cur = 0;
    for (int k0 = 0; k0 < Klen; k0 += BK) {
      if (k0 + BK < Klen) {
        const int nxt = cur ^ 1;
        const int kt2 = (koff + k0 + BK) >> 6;
        #pragma unroll
        for (int i = 0; i < 4; ++i)
          gload16(Ab + (size_t)(8 * i) * Kfull + k0 + BK, As[nxt] + AsWoff + i * 512);
        #pragma unroll
        for (int i = 0; i < NF; ++i) {
          int nn = n0 + rnW + 8 * i;
          gload16(Bt + ((size_t)(nn >> 6) * ktiles + kt2) * 4096 + (nn & 63) * 64 + kgrp * 8,
                  Bs[nxt] + BsWoff + i * 512);
        }
      }
      #pragma unroll
      for (int kh = 0; kh < 2; ++kh) {
        const int gs = g0 ^ (kh * 4);
        short8 a[4], b[NF];
        #pragma unroll
        for (int m = 0; m < 4; ++m) {
          int r = wrow + m * 16 + (lane & 15);
          a[m] = *(const short8*)(As[cur] + r * 64 + gs * 8);
        }
        #pragma unroll
        for (int n = 0; n < NF; ++n) {
          int r = wcol + n * 16 + (lane & 15);
          b[n] = *(const short8*)(Bs[cur] + r * 64 + gs * 8);
        }
        #pragma unroll
        for (int m = 0; m < 4; ++m)
          #pragma unroll
          for (int n = 0; n < NF; ++n)
            acc[m][n] = __builtin_amdgcn_mfma_f32_16x16x32_bf16(a[m], b[n], acc[m][n], 0, 0, 0);
      }
      __syncthreads();
      cur ^= 1;
    }
  }

  void* outp = (blockIdx.z == 0) ? Cout : Cout2;
  const int crow0 = m0 + wrow + (lane >> 4) * 4;
  const int ccol0 = n0 + wcol + (lane & 15);
  #pragma unroll
  for (int n = 0; n < NF; ++n) {
    int c = ccol0 + n * 16;
    float bv = 0.f;
    if (blockIdx.z == 0) {
      if (vTout) bv = (c < DMODEL) ? bias[c]
                    : (c < 2 * DMODEL) ? biasK[c - DMODEL] : biasV[c - 2 * DMODEL];
      else bv = bias[c];
    }
    bool tovT = (vTout != nullptr) && (c >= 2 * DMODEL);
    int hd = c - 2 * DMODEL;   // h*64+d when tovT
    #pragma unroll
    for (int m = 0; m < 4; ++m) {
      #pragma unroll
      for (int r = 0; r < 4; ++r) {
        float val = acc[m][n][r] + bv;
        if (relu) val = fmaxf(val, 0.f);
        int mr = crow0 + m * 16 + r;
        if (tovT) {
          vTout[((size_t)((mr >> 9) * NHEAD + (hd >> 6)) * HDIM + (hd & 63)) * SEQ + (mr & 511)] = f2bf(val);
        } else if (out_bf16) {
          ((unsigned short*)outp)[(size_t)mr * N + c] = f2bf(val);
        } else {
          ((float*)outp)[(size_t)mr * N + c] = val;
        }
      }
    }
  }
}

// ---------------------------------------------------------------------------
// MFMA flash attention, KVBLK=128 (R13/R17-measured-best form): K and V both
// staged in LDS via global_load_lds (slot = g ^ (row&7)); single-buffered,
// 2 barriers per KV iteration; setprio on MFMA clusters. [R19 lesson:
// V-direct global gathers in the PV loop cost +8us/dispatch -- keep staging.]
// ---------------------------------------------------------------------------
#define KT 128
__global__ __launch_bounds__(256) void attention_mfma_kernel(
    const unsigned short* __restrict__ qkv,  // [NTOK][2304] bf16 (Q|K|V)
    const unsigned short* __restrict__ vT,   // [(b*H+h)*64+d][SEQ] bf16
    const int* __restrict__ mask,            // [B][SEQ]
    unsigned short* __restrict__ out) {      // [NTOK][768] bf16
  unsigned orig = blockIdx.x;
  unsigned blk = (orig & 7) * (gridDim.x >> 3) + (orig >> 3);
  int qt0 = (blk % (SEQ / 64)) * 64;
  int h = (blk / (SEQ / 64)) % NHEAD;
  int b = blk / ((SEQ / 64) * NHEAD);
  int tid = threadIdx.x, lane = tid & 63, wave = tid >> 6;

  __shared__ unsigned short Ks[KT * 64];      // [key][dimgrp ^ (key&7)]
  __shared__ unsigned short Vs[64 * KT];      // [d][keygrp ^low3 (d&7)]
  __shared__ unsigned short Ps[4][16 * 136];  // per-wave P[q][key], stride 136
  __shared__ int msk_s[SEQ];

  if (tid < SEQ / 4) *(int4*)&msk_s[tid * 4] = *(const int4*)&mask[b * SEQ + tid * 4];

  int qrow = qt0 + wave * 16 + (lane & 15);
  const unsigned short* qp = qkv + (size_t)(b * SEQ + qrow) * QKVN + h * HDIM + (lane >> 4) * 8;
  short8 qf0 = *(const short8*)qp;
  short8 qf1 = *(const short8*)(qp + 32);

  float m_r[4], l_r[4];
  f32x4 acc_o[4];
  #pragma unroll
  for (int r = 0; r < 4; ++r) { m_r[r] = -3.0e38f; l_r[r] = 0.f; }
  #pragma unroll
  for (int n = 0; n < 4; ++n) acc_o[n] = (f32x4){0.f, 0.f, 0.f, 0.f};

  for (int kt = 0; kt < SEQ / KT; ++kt) {
    __syncthreads();
    // stage: Ks 128x8 chunks, Vs 64x16 chunks (1024 each; 4 per thread)
    #pragma unroll
    for (int it = 0; it < 4; ++it) {
      int ck = it * 256 + tid;
      int krow = ck >> 3, kg = ck & 7;
      gload16(qkv + (size_t)(b * SEQ + kt * KT + krow) * QKVN + DMODEL + h * HDIM + ((kg ^ (krow & 7)) * 8),
              Ks + ck * 8);
      int vrow = ck >> 4, vg = ck & 15;
      gload16(vT + (size_t)((b * NHEAD + h) * HDIM + vrow) * SEQ + kt * KT + ((vg ^ (vrow & 7)) * 8),
              Vs + ck * 8);
    }
    __syncthreads();

    // ---- S = Q K^T ----
    f32x4 acc_s[8];
    #pragma unroll
    for (int nf = 0; nf < 8; ++nf) acc_s[nf] = (f32x4){0.f, 0.f, 0.f, 0.f};
    __builtin_amdgcn_s_setprio(1);
    #pragma unroll
    for (int nf = 0; nf < 8; ++nf) {
      int rb = nf * 16 + (lane & 15);
      int G = lane >> 4;
      short8 kf0 = *(const short8*)(Ks + rb * 64 + ((G ^ (rb & 7)) * 8));
      short8 kf1 = *(const short8*)(Ks + rb * 64 + (((G + 4) ^ (rb & 7)) * 8));
      acc_s[nf] = __builtin_amdgcn_mfma_f32_16x16x32_bf16(qf0, kf0, acc_s[nf], 0, 0, 0);
      acc_s[nf] = __builtin_amdgcn_mfma_f32_16x16x32_bf16(qf1, kf1, acc_s[nf], 0, 0, 0);
    }
    __builtin_amdgcn_s_setprio(0);

    // ---- online softmax (scale+mask in place, then exp) ----
    float rmax[4];
    #pragma unroll
    for (int r = 0; r < 4; ++r) rmax[r] = -3.0e38f;
    #pragma unroll
    for (int nf = 0; nf < 8; ++nf) {
      int msk = msk_s[kt * KT + nf * 16 + (lane & 15)];
      #pragma unroll
      for (int r = 0; r < 4; ++r) {
        float s = acc_s[nf][r] * 0.125f;
        if (msk == 0) s = -1e9f;
        acc_s[nf][r] = s;
        rmax[r] = fmaxf(rmax[r], s);
      }
    }
    #pragma unroll
    for (int r = 0; r < 4; ++r) {
      rmax[r] = fmaxf(rmax[r], __shfl_xor(rmax[r], 1));
      rmax[r] = fmaxf(rmax[r], __shfl_xor(rmax[r], 2));
      rmax[r] = fmaxf(rmax[r], __shfl_xor(rmax[r], 4));
      rmax[r] = fmaxf(rmax[r], __shfl_xor(rmax[r], 8));
    }
    float corr[4], psum[4];
    #pragma unroll
    for (int r = 0; r < 4; ++r) {
      float mn = fmaxf(m_r[r], rmax[r]);
      corr[r] = expf(m_r[r] - mn);
      m_r[r] = mn;
      psum[r] = 0.f;
    }
    #pragma unroll
    for (int nf = 0; nf < 8; ++nf) {
      #pragma unroll
      for (int r = 0; r < 4; ++r) {
        float e = expf(acc_s[nf][r] - m_r[r]);
        psum[r] += e;
        Ps[wave][((lane >> 4) * 4 + r) * 136 + nf * 16 + (lane & 15)] = f2bf(e);
      }
    }
    #pragma unroll
    for (int r = 0; r < 4; ++r) {
      psum[r] += __shfl_xor(psum[r], 1);
      psum[r] += __shfl_xor(psum[r], 2);
      psum[r] += __shfl_xor(psum[r], 4);
      psum[r] += __shfl_xor(psum[r], 8);
      l_r[r] = l_r[r] * corr[r] + psum[r];
    }
    #pragma unroll
    for (int n = 0; n < 4; ++n)
      #pragma unroll
      for (int r = 0; r < 4; ++r)
        acc_o[n][r] *= corr[r];

    // ---- O += P V  (P rows q=lane&15; key chunks kh*32) ----
    short8 pa[4];
    #pragma unroll
    for (int kh = 0; kh < 4; ++kh)
      pa[kh] = *(const short8*)(&Ps[wave][(lane & 15) * 136 + kh * 32 + (lane >> 4) * 8]);
    __builtin_amdgcn_s_setprio(1);
    #pragma unroll
    for (int nd = 0; nd < 4; ++nd) {
      int rb = nd * 16 + (lane & 15);
      #pragma unroll
      for (int kh = 0; kh < 4; ++kh) {
        int G = (lane >> 4) + kh * 4;
        short8 vf = *(const short8*)(Vs + rb * KT + ((G ^ (rb & 7)) * 8));
        acc_o[nd] = __builtin_amdgcn_mfma_f32_16x16x32_bf16(pa[kh], vf, acc_o[nd], 0, 0, 0);
      }
    }
    __builtin_amdgcn_s_setprio(0);
  }

  #pragma unroll
  for (int r = 0; r < 4; ++r) {
    float inv = 1.0f / l_r[r];
    int row = qt0 + wave * 16 + (lane >> 4) * 4 + r;
    unsigned short* op = out + (size_t)(b * SEQ + row) * DMODEL + h * HDIM + (lane & 15);
    #pragma unroll
    for (int n = 0; n < 4; ++n)
      op[n * 16] = f2bf(acc_o[n][r] * inv);
  }
}

// ---------------------------------------------------------------------------
// LayerNorm over the bf16 residual stream, wave-per-token (no LDS/barriers).
// out = LN(xin (+ o) (+ o2)) in bf16. Stats in f32. In-place-safe per row.
// ---------------------------------------------------------------------------
__global__ __launch_bounds__(256) void ln_kernel(
    const unsigned short* __restrict__ xin, const unsigned short* __restrict__ o,
    const unsigned short* __restrict__ o2,
    unsigned short* __restrict__ outb,
    const float* __restrict__ g, const float* __restrict__ bta) {
  int lane = threadIdx.x & 63, wave = threadIdx.x >> 6;
  int n = blockIdx.x * 4 + wave;
  size_t base = (size_t)n * DMODEL;

  float v[12];
  float sum = 0.f;
  #pragma unroll
  for (int c = 0; c < 3; ++c) {
    int off = c * 256 + lane * 4;
    ushortx4 xv = *(const ushortx4*)(xin + base + off);
    #pragma unroll
    for (int j = 0; j < 4; ++j) v[c * 4 + j] = bf2f(xv[j]);
    if (o) {
      ushortx4 ov = *(const ushortx4*)(o + base + off);
      #pragma unroll
      for (int j = 0; j < 4; ++j) v[c * 4 + j] += bf2f(ov[j]);
    }
    if (o2) {
      ushortx4 ov = *(const ushortx4*)(o2 + base + off);
      #pragma unroll
      for (int j = 0; j < 4; ++j) v[c * 4 + j] += bf2f(ov[j]);
    }
    #pragma unroll
    for (int j = 0; j < 4; ++j) sum += v[c * 4 + j];
  }
  #pragma unroll
  for (int s = 1; s < 64; s <<= 1) sum += __shfl_xor(sum, s);
  float mu = sum * (1.0f / DMODEL);
  float var = 0.f;
  #pragma unroll
  for (int i = 0; i < 12; ++i) {
    float d = v[i] - mu;
    var += d * d;
  }
  #pragma unroll
  for (int s = 1; s < 64; s <<= 1) var += __shfl_xor(var, s);
  float rstd = rsqrtf(var * (1.0f / DMODEL) + 1e-5f);

  #pragma unroll
  for (int c = 0; c < 3; ++c) {
    int off = c * 256 + lane * 4;
    float4 gv = *(const float4*)(g + off);
    float4 bv = *(const float4*)(bta + off);
    ushortx4 rb;
    rb[0] = f2bf((v[c * 4 + 0] - mu) * rstd * gv.x + bv.x);
    rb[1] = f2bf((v[c * 4 + 1] - mu) * rstd * gv.y + bv.y);
    rb[2] = f2bf((v[c * 4 + 2] - mu) * rstd * gv.z + bv.z);
    rb[3] = f2bf((v[c * 4 + 3] - mu) * rstd * gv.w + bv.w);
    *(ushortx4*)(outb + base + off) = rb;
  }
}

// ---------------------------------------------------------------------------
// Mean-pool, stage 1 (bf16 input): 8 seq chunks of 64 rows -> partial[c][b][d]
// ---------------------------------------------------------------------------
__global__ __launch_bounds__(256) void pool_part_kernel(
    const unsigned short* __restrict__ xin, float* __restrict__ partial) {
  int blk = blockIdx.x;
  int chunk = blk / (BATCH * 3);
  int rem = blk % (BATCH * 3);
  int b = rem / 3, dc = rem % 3;
  int d = dc * 256 + threadIdx.x;
  float s_ = 0.f;
  for (int s = chunk * 64; s < chunk * 64 + 64; ++s)
    s_ += bf2f(xin[(size_t)(b * SEQ + s) * DMODEL + d]);
  partial[((size_t)chunk * BATCH + b) * DMODEL + d] = s_;
}

// ---------------------------------------------------------------------------
// Classifier: reduce 8 pool partials, logits = pooled @ Wfc + bfc, log_softmax
// ---------------------------------------------------------------------------
__global__ __launch_bounds__(256) void classifier_kernel(
    const float* __restrict__ partial, const float* __restrict__ Wfc,
    const float* __restrict__ bfc, float* __restrict__ out) {
  int b = blockIdx.x;
  int t = threadIdx.x;
  __shared__ float s0[256], s1[256];
  float acc0 = 0.f, acc1 = 0.f;
  for (int d = t; d < DMODEL; d += 256) {
    float p = 0.f;
    #pragma unroll
    for (int c = 0; c < 8; ++c)
      p += partial[((size_t)c * BATCH + b) * DMODEL + d];
    p *= (1.0f / SEQ);
    acc0 += p * Wfc[d * NCLS + 0];
    acc1 += p * Wfc[d * NCLS + 1];
  }
  s0[t] = acc0; s1[t] = acc1; __syncthreads();
  for (int off = 128; off; off >>= 1) {
    if (t < off) { s0[t] += s0[t + off]; s1[t] += s1[t + off]; }
    __syncthreads();
  }
  if (t == 0) {
    float l0 = s0[0] + bfc[0], l1 = s1[0] + bfc[1];
    float m = fmaxf(l0, l1);
    float lse = m + logf(expf(l0 - m) + expf(l1 - m));
    out[b * NCLS + 0] = l0 - lse;
    out[b * NCLS + 1] = l1 - lse;
  }
}

// ---------------------------------------------------------------------------
extern "C" void kernel_launch(void* const* d_in, const int* in_sizes, int n_in,
                              void* d_out, int out_size, void* d_ws, size_t ws_size,
                              hipStream_t stream) {
  const int*   text  = (const int*)d_in[0];
  const int*   mask  = (const int*)d_in[1];
  const float* emb   = (const float*)d_in[2];
  const float* Wq    = (const float*)d_in[3];
  const float* bq    = (const float*)d_in[4];
  const float* Wk    = (const float*)d_in[5];
  const float* bk    = (const float*)d_in[6];
  const float* Wv    = (const float*)d_in[7];
  const float* bv    = (const float*)d_in[8];
  const float* Wo    = (const float*)d_in[9];
  const float* bo    = (const float*)d_in[10];
  const float* W1    = (const float*)d_in[11];
  const float* b1    = (const float*)d_in[12];
  const float* W2    = (const float*)d_in[13];
  const float* b2    = (const float*)d_in[14];
  const float* ln1_g = (const float*)d_in[15];
  const float* ln1_b = (const float*)d_in[16];
  const float* ln2_g = (const float*)d_in[17];
  const float* ln2_b = (const float*)d_in[18];
  const float* lnf_g = (const float*)d_in[19];
  const float* lnf_b = (const float*)d_in[20];
  const float* Wfc   = (const float*)d_in[21];
  const float* bfc   = (const float*)d_in[22];

  const size_t ND = (size_t)NTOK * DMODEL;
  const size_t NF = (size_t)NTOK * FFDIM;
  const size_t WDD = (size_t)DMODEL * DMODEL;
  const size_t WDF = (size_t)DMODEL * FFDIM;

  float* partial = (float*)d_ws;                  // [8][B][D] pool partials
  unsigned short* xb   = (unsigned short*)(partial + 8 * BATCH * DMODEL);  // [N,D] residual stream (bf16)
  unsigned short* qkvb = xb + ND;                 // [N,2304]; also o/ffn2 out
  unsigned short* vTb  = qkvb + (size_t)NTOK * QKVN;  // [B*H*64][SEQ]
  unsigned short* aob  = vTb + ND;                // [N,D] attn out / ffn2 partial1 / final-LN
  unsigned short* h1b  = aob + ND;                // [N,FF]; first ND = o-proj partial1
  unsigned short* wqkvT = h1b + NF;               // 4 x tiled [2304][768]
  unsigned short* woT  = wqkvT + 4 * 3 * WDD;     // 4 x tiled [768][768]
  unsigned short* w1T  = woT + 4 * WDD;           // 4 x tiled [FF][D]
  unsigned short* w2T  = w1T + 4 * WDF;           // 4 x tiled [D][FF]
  unsigned short* ob   = qkvb;                    // alias: o-proj/ffn2 output

  dim3 gD64s(DMODEL / 64, NTOK / BM, 2);   // split-K=2 -> 768 blocks, TBN=64
  dim3 gQKV(QKVN / 128, NTOK / BM);        // (18, 32) = 576 blocks, TBN=128
  dim3 gF(FFDIM / 128, NTOK / BM);         // (24, 32) = 768 blocks, TBN=128

  embed_kernel<<<NTOK, 256, 0, stream>>>(text, emb, xb);
  wconv_all_kernel<<<4 * 432, 256, 0, stream>>>(
      Wq, Wk, Wv, Wo, W1, W2, wqkvT, woT, w1T, w2T);

  for (int l = 0; l < LAYERS; ++l) {
    // fused QKV projection (V written transposed to vTb)
    gemm_mfma_kernel<128><<<gQKV, 256, 0, stream>>>(
        xb, wqkvT + (size_t)l * 3 * WDD, bq + l * DMODEL, bk + l * DMODEL,
        bv + l * DMODEL, qkvb, nullptr, vTb, NTOK, QKVN, DMODEL, DMODEL, 1, 0);

    attention_mfma_kernel<<<BATCH * NHEAD * (SEQ / 64), 256, 0, stream>>>(
        qkvb, vTb, mask, aob);

    // O-proj split-K=2: z=0 -> ob (with bias), z=1 -> h1b (dead)
    gemm_mfma_kernel<64><<<gD64s, 256, 0, stream>>>(
        aob, woT + (size_t)l * WDD, bo + l * DMODEL, nullptr, nullptr,
        ob, h1b, nullptr, NTOK, DMODEL, DMODEL, DMODEL / 2, 1, 0);
    ln_kernel<<<NTOK / 4, 256, 0, stream>>>(xb, ob, h1b, xb,
                                            ln1_g + l * DMODEL, ln1_b + l * DMODEL);
    gemm_mfma_kernel<128><<<gF, 256, 0, stream>>>(
        xb, w1T + (size_t)l * WDF, b1 + l * FFDIM, nullptr, nullptr,
        h1b, nullptr, nullptr, NTOK, FFDIM, DMODEL, DMODEL, 1, 1);
    // FFN2 split-K=2: z=0 -> ob (with bias), z=1 -> aob (dead)
    gemm_mfma_kernel<64><<<gD64s, 256, 0, stream>>>(
        h1b, w2T + (size_t)l * WDF, b2 + l * DMODEL, nullptr, nullptr,
        ob, aob, nullptr, NTOK, DMODEL, FFDIM, FFDIM / 2, 1, 0);
    ln_kernel<<<NTOK / 4, 256, 0, stream>>>(xb, ob, aob, xb,
                                            ln2_g + l * DMODEL, ln2_b + l * DMODEL);
  }

  // final LN -> bf16 (into aob), then pool partials (bf16) + classify
  ln_kernel<<<NTOK / 4, 256, 0, stream>>>(xb, nullptr, nullptr, aob, lnf_g, lnf_b);
  pool_part_kernel<<<8 * BATCH * 3, 256, 0, stream>>>(aob, partial);
  classifier_kernel<<<BATCH, 256, 0, stream>>>(partial, Wfc, bfc, (float*)d_out);
}